// Round 5
// baseline (312.497 us; speedup 1.0000x reference)
//
#include <hip/hip_runtime.h>
#include <math.h>

#define N_NODES 8192
#define KNBR    32
#define PDIM    128
#define BINS    64
#define REL_CLIP 32
#define REL_DIM  66

typedef unsigned short ushort_t;
typedef short v8s  __attribute__((ext_vector_type(8)));
typedef short v4s_t __attribute__((ext_vector_type(4)));
typedef float v4f  __attribute__((ext_vector_type(4)));

__device__ __forceinline__ ushort_t f2bf(float f) {
    unsigned int u = __float_as_uint(f);
    u += 0x7fffu + ((u >> 16) & 1u);
    return (ushort_t)(u >> 16);
}
// gelu_tanh(x) == x * sigmoid(2*0.7978845608*(x + 0.044715 x^3)) (exact identity)
__device__ __forceinline__ float fast_gelu(float x) {
    float x2 = x * x;
    float y = x * fmaf(x2, 0.07135481627f, 1.5957691216f);
    float e = __expf(-y);
    return x / (1.f + e);
}
// M-dim permutation: position p = a*16 + hi*4 + r  ->  logical 32*(a>>1)+8*hi+4*(a&1)+r
__device__ __forceinline__ int fperm(int p) {
    int a = p >> 4, hi = (p >> 2) & 3, r = p & 3;
    return 32 * (a >> 1) + 8 * hi + 4 * (a & 1) + r;
}

// ---------------- prep: permuted bf16 weights ----------------
// Wcombp[p*128+k]  : pair weights, M-dim f-permuted, K logical (0..15 dist, 16..18 dir,
//                    19..27 rot, 28..42 pvec, 43..108 relpos one-hot, 109..127 zero)
// W1p[p*128+k]     : W1 out-dim f-permuted, K (pair) logical
// W2p[bin*256+k]   : plain transpose (no permutation needed)
// W_locTp[oc*256+k]: loc projection, out-dim f-permuted per 128-half (i then j)
// smalls: [0..256) b1 f-permuted | [256..384) ln_scale f-permuted | [384..512) ln_bias f-permuted
__global__ __launch_bounds__(256) void prep_kernel(
    const float* __restrict__ W_dist, const float* __restrict__ W_dir,
    const float* __restrict__ W_rot, const float* __restrict__ W_pvec,
    const float* __restrict__ W_relpos,
    const float* __restrict__ W1, const float* __restrict__ W2,
    const float* __restrict__ W_loc_i, const float* __restrict__ W_loc_j,
    const float* __restrict__ ln_scale, const float* __restrict__ ln_bias,
    const float* __restrict__ b1,
    ushort_t* __restrict__ Wcombp, ushort_t* __restrict__ W1p,
    ushort_t* __restrict__ W2p, ushort_t* __restrict__ W_locTp,
    float* __restrict__ smalls)
{
    int idx = blockIdx.x * 256 + threadIdx.x;
    if (idx < 16384) {
        int p = idx >> 7, k = idx & 127;
        int col = fperm(p);
        float v = 0.f;
        if (k < 16)       v = W_dist[k * PDIM + col];
        else if (k < 19)  v = W_dir[(k - 16) * PDIM + col];
        else if (k < 28)  v = W_rot[(k - 19) * PDIM + col];
        else if (k < 43)  v = W_pvec[(k - 28) * PDIM + col];
        else if (k < 109) v = W_relpos[(size_t)(k - 43) * PDIM + col];
        Wcombp[idx] = f2bf(v);
    } else if (idx < 49152) {
        int o = idx - 16384; int p = o >> 7, k = o & 127;
        W1p[o] = f2bf(W1[(size_t)k * 256 + fperm(p)]);
    } else if (idx < 65536) {
        int o = idx - 49152; int bin = o >> 8, k = o & 255;
        W2p[o] = f2bf(W2[(size_t)k * BINS + bin]);
    } else if (idx < 131072) {
        int o = idx - 65536; int oc = o >> 8, k = o & 255;
        float v = (oc < 128) ? W_loc_i[(size_t)k * 128 + fperm(oc)]
                             : W_loc_j[(size_t)k * 128 + fperm(oc - 128)];
        W_locTp[o] = f2bf(v);
    } else if (idx < 131584) {
        int o = idx - 131072;
        float v;
        if (o < 256)      v = b1[fperm(o)];
        else if (o < 384) v = ln_scale[fperm(o - 256)];
        else              v = ln_bias[fperm(o - 384)];
        smalls[o] = v;
    }
}

// ---------------- locframe: frames + MFMA local projections ----------------
__global__ __launch_bounds__(256) void locframe_kernel(
    const float* __restrict__ local, const float* __restrict__ pos,
    const ushort_t* __restrict__ W_locTp,
    float* __restrict__ R_ws, float* __restrict__ loci_ws, float* __restrict__ locj_ws)
{
    __shared__ __align__(16) ushort_t LB[32 * 264];
    const int tid = threadIdx.x;
    const int base = blockIdx.x * 32;
    const int wid = tid >> 6, lane = tid & 63, c15 = lane & 15, hi = lane >> 4;

    if (tid < 32) {  // frames
        const int n = base + tid;
        const float* pp = pos + (size_t)n * 15;
        float nx = pp[0], ny = pp[1], nz = pp[2];
        float cax = pp[3], cay = pp[4], caz = pp[5];
        float cx = pp[6], cy = pp[7], cz = pp[8];
        float e1x = cx - cax, e1y = cy - cay, e1z = cz - caz;
        float n1 = sqrtf(e1x*e1x + e1y*e1y + e1z*e1z) + 1e-8f;
        e1x /= n1; e1y /= n1; e1z /= n1;
        float v2x = nx - cax, v2y = ny - cay, v2z = nz - caz;
        float dp = v2x*e1x + v2y*e1y + v2z*e1z;
        float wx = v2x - dp*e1x, wy = v2y - dp*e1y, wz = v2z - dp*e1z;
        float n2 = sqrtf(wx*wx + wy*wy + wz*wz) + 1e-8f;
        float e2x = wx/n2, e2y = wy/n2, e2z = wz/n2;
        float* R = R_ws + (size_t)n * 9;
        R[0] = e1x; R[1] = e1y; R[2] = e1z;
        R[3] = e2x; R[4] = e2y; R[5] = e2z;
        R[6] = e1y*e2z - e1z*e2y;
        R[7] = e1z*e2x - e1x*e2z;
        R[8] = e1x*e2y - e1y*e2x;
    }
    #pragma unroll
    for (int it = 0; it < 8; ++it) {
        int f = tid + it * 256;
        int row = f >> 6, kc = f & 63;
        float4 L = *(const float4*)&local[((size_t)(base + row)) * 256 + kc * 4];
        v4s_t u;
        u[0] = (short)f2bf(L.x); u[1] = (short)f2bf(L.y);
        u[2] = (short)f2bf(L.z); u[3] = (short)f2bf(L.w);
        *(v4s_t*)&LB[row * 264 + kc * 4] = u;
    }
    __syncthreads();

    v4f acc[4][2];
    #pragma unroll
    for (int a = 0; a < 4; ++a)
        #pragma unroll
        for (int b = 0; b < 2; ++b) { acc[a][b][0]=0.f; acc[a][b][1]=0.f; acc[a][b][2]=0.f; acc[a][b][3]=0.f; }
    #pragma unroll
    for (int ks = 0; ks < 8; ++ks) {
        v8s bF[2];
        #pragma unroll
        for (int bt = 0; bt < 2; ++bt)
            bF[bt] = *(const v8s*)&LB[(bt*16 + c15) * 264 + ks*32 + hi*8];
        #pragma unroll
        for (int act = 0; act < 4; ++act) {
            v8s aF = *(const v8s*)&W_locTp[(size_t)(wid*64 + act*16 + c15) * 256 + ks*32 + hi*8];
            #pragma unroll
            for (int bt = 0; bt < 2; ++bt)
                acc[act][bt] = __builtin_amdgcn_mfma_f32_16x16x32_bf16(aF, bF[bt], acc[act][bt], 0, 0, 0);
        }
    }
    #pragma unroll
    for (int act = 0; act < 4; ++act) {
        const int oc0 = wid*64 + act*16 + hi*4;
        #pragma unroll
        for (int bt = 0; bt < 2; ++bt) {
            const int lrow = bt*16 + c15;
            float4 v;
            v.x = acc[act][bt][0]; v.y = acc[act][bt][1];
            v.z = acc[act][bt][2]; v.w = acc[act][bt][3];
            if (oc0 < 128)
                *(float4*)&loci_ws[(size_t)(base + lrow) * 128 + oc0] = v;
            else
                *(float4*)&locj_ws[(size_t)(base + lrow) * 128 + (oc0 - 128)] = v;
        }
    }
}

// ---------------- pair kernel: zero LDS, zero barriers, register dataflow ----------------
// 4096 blocks x 256 thr; wave owns 16 rows; lane (hi,c15): row = c15-row, channel-slice = hi
__global__ __launch_bounds__(256, 4) void pair_kernel(
    const float* __restrict__ pos, const int* __restrict__ neighbours,
    const int* __restrict__ resi, const int* __restrict__ chain,
    const int* __restrict__ batch, const int* __restrict__ mask,
    const float* __restrict__ b2,
    const float* __restrict__ R_ws, const float* __restrict__ loci_ws,
    const float* __restrict__ locj_ws,
    const ushort_t* __restrict__ Wcombp, const ushort_t* __restrict__ W1p,
    const ushort_t* __restrict__ W2p, const float* __restrict__ smalls,
    float* __restrict__ out)
{
    const int tid = threadIdx.x;
    const int lane = tid & 63;
    const int c15 = lane & 15;
    const int hi = lane >> 4;
    const int row = blockIdx.x * 64 + (tid >> 6) * 16 + c15;
    const int node = row >> 5;
    const int nb = neighbours[(size_t)node * KNBR + (row & 31)];
    const int j = nb < 0 ? 0 : nb;

    int rel = resi[j] - resi[node];
    rel = rel < -REL_CLIP ? -REL_CLIP : (rel > REL_CLIP ? REL_CLIP : rel);
    rel += REL_CLIP;
    const int code = ((chain[j] == chain[node]) && (batch[j] == batch[node])) ? rel : (REL_DIM - 1);

    float Ri[9];
    #pragma unroll
    for (int q = 0; q < 9; ++q) Ri[q] = R_ws[(size_t)node * 9 + q];
    const float cax = pos[(size_t)node*15 + 3], cay = pos[(size_t)node*15 + 4], caz = pos[(size_t)node*15 + 5];
    const float* pj = pos + (size_t)j * 15;
    const float dx = pj[3] - cax, dy = pj[4] - cay, dz = pj[5] - caz;

    // ---- features: lane computes exactly its B-frag chunks (logical k = ks*32 + hi*8 + t) ----
    v8s featF[4];
    #pragma unroll
    for (int ks = 1; ks < 4; ++ks) {           // uniform one-hot / zeros (k>108 auto-false)
        const int cb = ks*32 + hi*8 - 43;
        v8s v;
        #pragma unroll
        for (int t = 0; t < 8; ++t) v[t] = (short)((code == cb + t) ? 0x3F80 : 0);
        featF[ks] = v;
    }
    #define DOTR(b,X,Y,Z) (Ri[(b)*3]*(X) + Ri[(b)*3+1]*(Y) + Ri[(b)*3+2]*(Z))
    const float d = sqrtf(dx*dx + dy*dy + dz*dz);
    if (hi == 0) {
        v8s v;
        #pragma unroll
        for (int r = 0; r < 8; ++r) { float dd = d - (22.f/15.f)*r; v[r] = (short)f2bf(__expf(-dd*dd*(1.f/3.78125f))); }
        featF[0] = v;
        float p2x = pj[6]-cax, p2y = pj[7]-cay, p2z = pj[8]-caz;
        float p3x = pj[9]-cax, p3y = pj[10]-cay, p3z = pj[11]-caz;
        v8s w;
        w[0] = (short)f2bf(DOTR(1, dx, dy, dz));
        w[1] = (short)f2bf(DOTR(2, dx, dy, dz));
        w[2] = (short)f2bf(DOTR(0, p2x, p2y, p2z));
        w[3] = (short)f2bf(DOTR(1, p2x, p2y, p2z));
        w[4] = (short)f2bf(DOTR(2, p2x, p2y, p2z));
        w[5] = (short)f2bf(DOTR(0, p3x, p3y, p3z));
        w[6] = (short)f2bf(DOTR(1, p3x, p3y, p3z));
        w[7] = (short)f2bf(DOTR(2, p3x, p3y, p3z));
        featF[1] = w;
    } else if (hi == 1) {
        v8s v;
        #pragma unroll
        for (int r = 0; r < 8; ++r) { float dd = d - (22.f/15.f)*(r+8); v[r] = (short)f2bf(__expf(-dd*dd*(1.f/3.78125f))); }
        featF[0] = v;
        float p4x = pj[12]-cax, p4y = pj[13]-cay, p4z = pj[14]-caz;
        v8s w = featF[1];
        w[0] = (short)f2bf(DOTR(0, p4x, p4y, p4z));
        w[1] = (short)f2bf(DOTR(1, p4x, p4y, p4z));
        w[2] = (short)f2bf(DOTR(2, p4x, p4y, p4z));
        featF[1] = w;
    } else if (hi == 2) {
        float inv = 1.f / (d + 1e-8f);
        float ux = dx*inv, uy = dy*inv, uz = dz*inv;
        float Rj[9];
        #pragma unroll
        for (int q = 0; q < 9; ++q) Rj[q] = R_ws[(size_t)j * 9 + q];
        #define ROT(b,c) (Ri[(b)*3]*Rj[(c)*3] + Ri[(b)*3+1]*Rj[(c)*3+1] + Ri[(b)*3+2]*Rj[(c)*3+2])
        v8s v;
        v[0] = (short)f2bf(DOTR(0, ux, uy, uz));
        v[1] = (short)f2bf(DOTR(1, ux, uy, uz));
        v[2] = (short)f2bf(DOTR(2, ux, uy, uz));
        v[3] = (short)f2bf(ROT(0,0));
        v[4] = (short)f2bf(ROT(0,1));
        v[5] = (short)f2bf(ROT(0,2));
        v[6] = (short)f2bf(ROT(1,0));
        v[7] = (short)f2bf(ROT(1,1));
        featF[0] = v;
        #undef ROT
    } else {
        float Rj[9];
        #pragma unroll
        for (int q = 0; q < 9; ++q) Rj[q] = R_ws[(size_t)j * 9 + q];
        #define ROT(b,c) (Ri[(b)*3]*Rj[(c)*3] + Ri[(b)*3+1]*Rj[(c)*3+1] + Ri[(b)*3+2]*Rj[(c)*3+2])
        float p0x = pj[0]-cax, p0y = pj[1]-cay, p0z = pj[2]-caz;
        v8s v;
        v[0] = (short)f2bf(ROT(1,2));
        v[1] = (short)f2bf(ROT(2,0));
        v[2] = (short)f2bf(ROT(2,1));
        v[3] = (short)f2bf(ROT(2,2));
        v[4] = (short)f2bf(DOTR(0, p0x, p0y, p0z));
        v[5] = (short)f2bf(DOTR(1, p0x, p0y, p0z));
        v[6] = (short)f2bf(DOTR(2, p0x, p0y, p0z));
        v[7] = (short)f2bf(DOTR(0, dx, dy, dz));
        featF[0] = v;
        #undef ROT
    }
    #undef DOTR

    // ---- P1: pair GEMM (swapped, M = f-permuted pair channels), epilogue + LN in-reg ----
    v4f pacc[8];
    #pragma unroll
    for (int a = 0; a < 8; ++a) { pacc[a][0]=0.f; pacc[a][1]=0.f; pacc[a][2]=0.f; pacc[a][3]=0.f; }
    #pragma unroll
    for (int ks = 0; ks < 4; ++ks) {
        v8s bF = featF[ks];
        #pragma unroll
        for (int a = 0; a < 8; ++a) {
            v8s aF = *(const v8s*)&Wcombp[(size_t)(a*16 + c15) * 128 + ks*32 + hi*8];
            pacc[a] = __builtin_amdgcn_mfma_f32_16x16x32_bf16(aF, bF, pacc[a], 0, 0, 0);
        }
    }
    const float pm = (mask[node] != 0 && mask[j] != 0 && nb != -1) ? 1.f : 0.f;
    float s = 0.f, sq = 0.f;
    #pragma unroll
    for (int a = 0; a < 8; ++a) {
        float4 li = *(const float4*)&loci_ws[(size_t)node * 128 + a*16 + hi*4];
        float4 lj = *(const float4*)&locj_ws[(size_t)j * 128 + a*16 + hi*4];
        float v0 = (pacc[a][0] + li.x + lj.x) * pm;
        float v1 = (pacc[a][1] + li.y + lj.y) * pm;
        float v2 = (pacc[a][2] + li.z + lj.z) * pm;
        float v3 = (pacc[a][3] + li.w + lj.w) * pm;
        pacc[a][0] = v0; pacc[a][1] = v1; pacc[a][2] = v2; pacc[a][3] = v3;
        s += v0 + v1 + v2 + v3;
        sq += v0*v0 + v1*v1 + v2*v2 + v3*v3;
    }
    s += __shfl_xor(s, 16, 64);  sq += __shfl_xor(sq, 16, 64);
    s += __shfl_xor(s, 32, 64);  sq += __shfl_xor(sq, 32, 64);
    const float mu = s * (1.f/128.f);
    const float rstd = rsqrtf(sq * (1.f/128.f) - mu*mu + 1e-5f);
    const float nm = -mu * rstd;
    v8s pairF[4];
    #pragma unroll
    for (int a = 0; a < 8; ++a) {
        float4 sc = *(const float4*)&smalls[256 + a*16 + hi*4];
        float4 bb = *(const float4*)&smalls[384 + a*16 + hi*4];
        pairF[a>>1][(a&1)*4 + 0] = (short)f2bf(fmaf(fmaf(pacc[a][0], rstd, nm), sc.x, bb.x));
        pairF[a>>1][(a&1)*4 + 1] = (short)f2bf(fmaf(fmaf(pacc[a][1], rstd, nm), sc.y, bb.y));
        pairF[a>>1][(a&1)*4 + 2] = (short)f2bf(fmaf(fmaf(pacc[a][2], rstd, nm), sc.z, bb.z));
        pairF[a>>1][(a&1)*4 + 3] = (short)f2bf(fmaf(fmaf(pacc[a][3], rstd, nm), sc.w, bb.w));
    }

    // ---- P4: MLP1 (swapped, M = f-permuted hidden), two halves, gelu in-reg ----
    v8s hidF[8];
    #pragma unroll
    for (int half = 0; half < 2; ++half) {
        v4f acc1[8];
        #pragma unroll
        for (int a = 0; a < 8; ++a) { acc1[a][0]=0.f; acc1[a][1]=0.f; acc1[a][2]=0.f; acc1[a][3]=0.f; }
        #pragma unroll
        for (int ks = 0; ks < 4; ++ks) {
            v8s bF = pairF[ks];
            #pragma unroll
            for (int a8 = 0; a8 < 8; ++a8) {
                const int a = half*8 + a8;
                v8s aF = *(const v8s*)&W1p[(size_t)(a*16 + c15) * 128 + ks*32 + hi*8];
                acc1[a8] = __builtin_amdgcn_mfma_f32_16x16x32_bf16(aF, bF, acc1[a8], 0, 0, 0);
            }
        }
        #pragma unroll
        for (int a8 = 0; a8 < 8; ++a8) {
            const int a = half*8 + a8;
            float4 bv = *(const float4*)&smalls[a*16 + hi*4];
            hidF[a>>1][(a&1)*4 + 0] = (short)f2bf(fast_gelu(acc1[a8][0] + bv.x));
            hidF[a>>1][(a&1)*4 + 1] = (short)f2bf(fast_gelu(acc1[a8][1] + bv.y));
            hidF[a>>1][(a&1)*4 + 2] = (short)f2bf(fast_gelu(acc1[a8][2] + bv.z));
            hidF[a>>1][(a&1)*4 + 3] = (short)f2bf(fast_gelu(acc1[a8][3] + bv.w));
        }
    }

    // ---- P5: MLP2 + log_softmax in-reg ----
    v4f acc2[4];
    #pragma unroll
    for (int a = 0; a < 4; ++a) { acc2[a][0]=0.f; acc2[a][1]=0.f; acc2[a][2]=0.f; acc2[a][3]=0.f; }
    #pragma unroll
    for (int ks = 0; ks < 8; ++ks) {
        v8s bF = hidF[ks];
        #pragma unroll
        for (int a = 0; a < 4; ++a) {
            v8s aF = *(const v8s*)&W2p[(size_t)(a*16 + c15) * 256 + ks*32 + hi*8];
            acc2[a] = __builtin_amdgcn_mfma_f32_16x16x32_bf16(aF, bF, acc2[a], 0, 0, 0);
        }
    }
    float lv[16];
    #pragma unroll
    for (int a = 0; a < 4; ++a) {
        float4 bv = *(const float4*)&b2[a*16 + hi*4];
        lv[a*4+0] = acc2[a][0] + bv.x;
        lv[a*4+1] = acc2[a][1] + bv.y;
        lv[a*4+2] = acc2[a][2] + bv.z;
        lv[a*4+3] = acc2[a][3] + bv.w;
    }
    float M = lv[0];
    #pragma unroll
    for (int q = 1; q < 16; ++q) M = fmaxf(M, lv[q]);
    M = fmaxf(M, __shfl_xor(M, 16, 64));
    M = fmaxf(M, __shfl_xor(M, 32, 64));
    float S = 0.f;
    #pragma unroll
    for (int q = 0; q < 16; ++q) S += __expf(lv[q] - M);
    S += __shfl_xor(S, 16, 64);
    S += __shfl_xor(S, 32, 64);
    const float lz = M + __logf(S);
    #pragma unroll
    for (int a = 0; a < 4; ++a) {
        float4 o;
        o.x = lv[a*4+0] - lz; o.y = lv[a*4+1] - lz;
        o.z = lv[a*4+2] - lz; o.w = lv[a*4+3] - lz;
        *(float4*)&out[(size_t)row * 64 + a*16 + hi*4] = o;
    }
}

extern "C" void kernel_launch(void* const* d_in, const int* in_sizes, int n_in,
                              void* d_out, int out_size, void* d_ws, size_t ws_size,
                              hipStream_t stream) {
    (void)in_sizes; (void)n_in; (void)out_size; (void)ws_size;
    const float* local   = (const float*)d_in[0];
    const float* pos     = (const float*)d_in[1];
    const int* neighbours= (const int*)d_in[2];
    const int* resi      = (const int*)d_in[3];
    const int* chain     = (const int*)d_in[4];
    const int* batch     = (const int*)d_in[5];
    const int* mask      = (const int*)d_in[6];
    const float* W_relpos= (const float*)d_in[7];
    const float* W_dist  = (const float*)d_in[8];
    const float* W_dir   = (const float*)d_in[9];
    const float* W_rot   = (const float*)d_in[10];
    const float* W_pvec  = (const float*)d_in[11];
    const float* W_loc_i = (const float*)d_in[12];
    const float* W_loc_j = (const float*)d_in[13];
    const float* ln_scale= (const float*)d_in[14];
    const float* ln_bias = (const float*)d_in[15];
    const float* W1      = (const float*)d_in[16];
    const float* b1      = (const float*)d_in[17];
    const float* W2      = (const float*)d_in[18];
    const float* b2      = (const float*)d_in[19];
    float* out = (float*)d_out;

    float* R_ws    = (float*)d_ws;                          // 8192*9 f32
    float* loci_ws = R_ws + (size_t)N_NODES * 9;            // 8192*128 f32
    float* locj_ws = loci_ws + (size_t)N_NODES * PDIM;      // 8192*128 f32
    ushort_t* Wcombp = (ushort_t*)(locj_ws + (size_t)N_NODES * PDIM); // 16384
    ushort_t* W1p    = Wcombp + 16384;                      // 32768
    ushort_t* W2p    = W1p + 32768;                         // 16384
    ushort_t* W_locTp= W2p + 16384;                         // 65536
    float* smalls    = (float*)(W_locTp + 65536);           // 512 f32

    hipLaunchKernelGGL(prep_kernel, dim3(514), dim3(256), 0, stream,
                       W_dist, W_dir, W_rot, W_pvec, W_relpos, W1, W2,
                       W_loc_i, W_loc_j, ln_scale, ln_bias, b1,
                       Wcombp, W1p, W2p, W_locTp, smalls);
    hipLaunchKernelGGL(locframe_kernel, dim3(N_NODES / 32), dim3(256), 0, stream,
                       local, pos, W_locTp, R_ws, loci_ws, locj_ws);
    hipLaunchKernelGGL(pair_kernel, dim3(N_NODES / 2), dim3(256), 0, stream,
                       pos, neighbours, resi, chain, batch, mask, b2,
                       R_ws, loci_ws, locj_ws, Wcombp, W1p, W2p, smalls, out);
}

// Round 6
// 216.779 us; speedup vs baseline: 1.4415x; 1.4415x over previous
//
#include <hip/hip_runtime.h>
#include <math.h>

#define N_NODES 8192
#define KNBR    32
#define PDIM    128
#define BINS    64
#define REL_CLIP 32
#define REL_DIM  66

typedef unsigned short ushort_t;
typedef short v8s  __attribute__((ext_vector_type(8)));
typedef short v4s_t __attribute__((ext_vector_type(4)));
typedef float v4f  __attribute__((ext_vector_type(4)));

__device__ __forceinline__ ushort_t f2bf(float f) {
    unsigned int u = __float_as_uint(f);
    u += 0x7fffu + ((u >> 16) & 1u);
    return (ushort_t)(u >> 16);
}
// gelu_tanh(x) == x * sigmoid(2*0.7978845608*(x + 0.044715 x^3)) (exact identity)
__device__ __forceinline__ float fast_gelu(float x) {
    float x2 = x * x;
    float y = x * fmaf(x2, 0.07135481627f, 1.5957691216f);
    float e = __expf(-y);
    return x / (1.f + e);
}

// ---------------- prep: bf16 transposed/combined weights ----------------
// Wcomb[128 col][128 k]: 0..15 dist, 16..18 dir, 19..27 rot, 28..42 pvec,
//                        43..108 relpos one-hot, 109..127 zero
// W1T[256][128], W2T[64][256], W_locT[256][256] (oc<128: W_loc_i, else W_loc_j)
__global__ __launch_bounds__(256) void prep_kernel(
    const float* __restrict__ W_dist, const float* __restrict__ W_dir,
    const float* __restrict__ W_rot, const float* __restrict__ W_pvec,
    const float* __restrict__ W_relpos,
    const float* __restrict__ W1, const float* __restrict__ W2,
    const float* __restrict__ W_loc_i, const float* __restrict__ W_loc_j,
    ushort_t* __restrict__ Wcomb, ushort_t* __restrict__ W1T,
    ushort_t* __restrict__ W2T, ushort_t* __restrict__ W_locT)
{
    int idx = blockIdx.x * 256 + threadIdx.x;
    if (idx < 16384) {
        int col = idx >> 7, k = idx & 127;
        float v = 0.f;
        if (k < 16)       v = W_dist[k * PDIM + col];
        else if (k < 19)  v = W_dir[(k - 16) * PDIM + col];
        else if (k < 28)  v = W_rot[(k - 19) * PDIM + col];
        else if (k < 43)  v = W_pvec[(k - 28) * PDIM + col];
        else if (k < 109) v = W_relpos[(size_t)(k - 43) * PDIM + col];
        Wcomb[idx] = f2bf(v);
    } else if (idx < 49152) {
        int o = idx - 16384;
        int col = o >> 7, k = o & 127;
        W1T[o] = f2bf(W1[(size_t)k * 256 + col]);
    } else if (idx < 65536) {
        int o = idx - 49152;
        int col = o >> 8, k = o & 255;
        W2T[o] = f2bf(W2[(size_t)k * BINS + col]);
    } else if (idx < 131072) {
        int o = idx - 65536;
        int oc = o >> 8, k = o & 255;
        float v = (oc < 128) ? W_loc_i[(size_t)k * 128 + oc]
                             : W_loc_j[(size_t)k * 128 + (oc - 128)];
        W_locT[o] = f2bf(v);
    }
}

// ---------------- locframe: frames + MFMA local projections ----------------
__global__ __launch_bounds__(256) void locframe_kernel(
    const float* __restrict__ local, const float* __restrict__ pos,
    const ushort_t* __restrict__ W_locT,
    float* __restrict__ R_ws, float* __restrict__ loci_ws, float* __restrict__ locj_ws)
{
    __shared__ __align__(16) ushort_t LB[32 * 264];
    const int tid = threadIdx.x;
    const int base = blockIdx.x * 32;
    const int wid = tid >> 6, lane = tid & 63, c15 = lane & 15, hi = lane >> 4;

    if (tid < 32) {  // frames
        const int n = base + tid;
        const float* pp = pos + (size_t)n * 15;
        float nx = pp[0], ny = pp[1], nz = pp[2];
        float cax = pp[3], cay = pp[4], caz = pp[5];
        float cx = pp[6], cy = pp[7], cz = pp[8];
        float e1x = cx - cax, e1y = cy - cay, e1z = cz - caz;
        float n1 = sqrtf(e1x*e1x + e1y*e1y + e1z*e1z) + 1e-8f;
        e1x /= n1; e1y /= n1; e1z /= n1;
        float v2x = nx - cax, v2y = ny - cay, v2z = nz - caz;
        float dp = v2x*e1x + v2y*e1y + v2z*e1z;
        float wx = v2x - dp*e1x, wy = v2y - dp*e1y, wz = v2z - dp*e1z;
        float n2 = sqrtf(wx*wx + wy*wy + wz*wz) + 1e-8f;
        float e2x = wx/n2, e2y = wy/n2, e2z = wz/n2;
        float* R = R_ws + (size_t)n * 9;
        R[0] = e1x; R[1] = e1y; R[2] = e1z;
        R[3] = e2x; R[4] = e2y; R[5] = e2z;
        R[6] = e1y*e2z - e1z*e2y;
        R[7] = e1z*e2x - e1x*e2z;
        R[8] = e1x*e2y - e1y*e2x;
    }
    #pragma unroll
    for (int it = 0; it < 8; ++it) {
        int f = tid + it * 256;
        int row = f >> 6, kc = f & 63;
        float4 L = *(const float4*)&local[((size_t)(base + row)) * 256 + kc * 4];
        v4s_t u;
        u[0] = (short)f2bf(L.x); u[1] = (short)f2bf(L.y);
        u[2] = (short)f2bf(L.z); u[3] = (short)f2bf(L.w);
        *(v4s_t*)&LB[row * 264 + kc * 4] = u;
    }
    __syncthreads();

    v4f acc[4][2];
    #pragma unroll
    for (int a = 0; a < 4; ++a)
        #pragma unroll
        for (int b = 0; b < 2; ++b) { acc[a][b][0]=0.f; acc[a][b][1]=0.f; acc[a][b][2]=0.f; acc[a][b][3]=0.f; }
    #pragma unroll
    for (int ks = 0; ks < 8; ++ks) {
        v8s bF[2];
        #pragma unroll
        for (int bt = 0; bt < 2; ++bt)
            bF[bt] = *(const v8s*)&LB[(bt*16 + c15) * 264 + ks*32 + hi*8];
        #pragma unroll
        for (int act = 0; act < 4; ++act) {
            v8s aF = *(const v8s*)&W_locT[(size_t)(wid*64 + act*16 + c15) * 256 + ks*32 + hi*8];
            #pragma unroll
            for (int bt = 0; bt < 2; ++bt)
                acc[act][bt] = __builtin_amdgcn_mfma_f32_16x16x32_bf16(aF, bF[bt], acc[act][bt], 0, 0, 0);
        }
    }
    #pragma unroll
    for (int act = 0; act < 4; ++act) {
        const int oc0 = wid*64 + act*16 + hi*4;
        #pragma unroll
        for (int bt = 0; bt < 2; ++bt) {
            const int lrow = bt*16 + c15;
            float4 v;
            v.x = acc[act][bt][0]; v.y = acc[act][bt][1];
            v.z = acc[act][bt][2]; v.w = acc[act][bt][3];
            if (oc0 < 128)
                *(float4*)&loci_ws[(size_t)(base + lrow) * 128 + oc0] = v;
            else
                *(float4*)&locj_ws[(size_t)(base + lrow) * 128 + (oc0 - 128)] = v;
        }
    }
}

// ---------------- pair kernel: 4096 blocks x 256 thr, 64 rows (2 nodes) ----------------
// P1 swapped (reg features+LN), P4 wave-split hidden (amortized W1), P5 swapped (reg softmax)
__global__ __launch_bounds__(256, 3) void pair_kernel(
    const float* __restrict__ pos, const int* __restrict__ neighbours,
    const int* __restrict__ resi, const int* __restrict__ chain,
    const int* __restrict__ batch, const int* __restrict__ mask,
    const float* __restrict__ ln_scale, const float* __restrict__ ln_bias,
    const float* __restrict__ b1, const float* __restrict__ b2,
    const float* __restrict__ R_ws, const float* __restrict__ loci_ws,
    const float* __restrict__ locj_ws,
    const ushort_t* __restrict__ Wcomb, const ushort_t* __restrict__ W1T,
    const ushort_t* __restrict__ W2T, float* __restrict__ out)
{
    __shared__ __align__(16) ushort_t PB[64 * 128];   // pairB bf16, 16KB, 256B stride
    __shared__ __align__(16) ushort_t HT[64 * 256];   // hidden bf16, 32KB, 512B stride
    __shared__ float smalls[576];                     // 0:lnsc 128:lnb 256:b1 512:b2

    const int tid = threadIdx.x;
    const int ib = blockIdx.x;
    const int wid = tid >> 6, lane = tid & 63, c15 = lane & 15, hi = lane >> 4;
    const int brow = wid * 16 + c15;              // block-local pair row (0..63)
    const int row  = ib * 64 + brow;              // global pair row
    const int node = row >> 5;
    const int sw = c15 & 7;

    const int nb = neighbours[(size_t)node * KNBR + (row & 31)];
    const int j = nb < 0 ? 0 : nb;

    // ---- T14 early: loc prefetch into registers (consumed after P1 MFMAs) ----
    float4 liR[8], ljR[8];
    #pragma unroll
    for (int a = 0; a < 8; ++a) {
        liR[a] = *(const float4*)&loci_ws[(size_t)node * 128 + a*16 + hi*4];
        ljR[a] = *(const float4*)&locj_ws[(size_t)j * 128 + a*16 + hi*4];
    }
    const int mi = mask[node], mj = mask[j];

    // ---- stage smalls ----
    if (tid < 144) {
        int t4 = tid * 4;
        float4 v;
        if (tid < 32)       v = *(const float4*)&ln_scale[t4];
        else if (tid < 64)  v = *(const float4*)&ln_bias[t4 - 128];
        else if (tid < 128) v = *(const float4*)&b1[t4 - 256];
        else                v = *(const float4*)&b2[t4 - 512];
        *(float4*)&smalls[t4] = v;
    }
    __syncthreads();   // bar0: smalls ready

    // ---- features per-lane: B-frag slices k = ks*32 + hi*8 + t ----
    int rel = resi[j] - resi[node];
    rel = rel < -REL_CLIP ? -REL_CLIP : (rel > REL_CLIP ? REL_CLIP : rel);
    rel += REL_CLIP;
    const int code = ((chain[j] == chain[node]) && (batch[j] == batch[node])) ? rel : (REL_DIM - 1);

    float Ri[9];
    #pragma unroll
    for (int q = 0; q < 9; ++q) Ri[q] = R_ws[(size_t)node * 9 + q];
    const float cax = pos[(size_t)node*15 + 3], cay = pos[(size_t)node*15 + 4], caz = pos[(size_t)node*15 + 5];
    const float* pj = pos + (size_t)j * 15;
    const float dx = pj[3] - cax, dy = pj[4] - cay, dz = pj[5] - caz;

    v8s featF[4];
    #pragma unroll
    for (int ks = 1; ks < 4; ++ks) {           // uniform one-hot / zeros
        const int cb = ks*32 + hi*8 - 43;
        v8s v;
        #pragma unroll
        for (int t = 0; t < 8; ++t) v[t] = (short)((code == cb + t) ? 0x3F80 : 0);
        featF[ks] = v;
    }
    #define DOTR(b,X,Y,Z) (Ri[(b)*3]*(X) + Ri[(b)*3+1]*(Y) + Ri[(b)*3+2]*(Z))
    const float d = sqrtf(dx*dx + dy*dy + dz*dz);
    if (hi == 0) {
        v8s v;
        #pragma unroll
        for (int r = 0; r < 8; ++r) { float dd = d - (22.f/15.f)*r; v[r] = (short)f2bf(__expf(-dd*dd*(1.f/3.78125f))); }
        featF[0] = v;
        float p2x = pj[6]-cax, p2y = pj[7]-cay, p2z = pj[8]-caz;
        float p3x = pj[9]-cax, p3y = pj[10]-cay, p3z = pj[11]-caz;
        v8s w;
        w[0] = (short)f2bf(DOTR(1, dx, dy, dz));
        w[1] = (short)f2bf(DOTR(2, dx, dy, dz));
        w[2] = (short)f2bf(DOTR(0, p2x, p2y, p2z));
        w[3] = (short)f2bf(DOTR(1, p2x, p2y, p2z));
        w[4] = (short)f2bf(DOTR(2, p2x, p2y, p2z));
        w[5] = (short)f2bf(DOTR(0, p3x, p3y, p3z));
        w[6] = (short)f2bf(DOTR(1, p3x, p3y, p3z));
        w[7] = (short)f2bf(DOTR(2, p3x, p3y, p3z));
        featF[1] = w;
    } else if (hi == 1) {
        v8s v;
        #pragma unroll
        for (int r = 0; r < 8; ++r) { float dd = d - (22.f/15.f)*(r+8); v[r] = (short)f2bf(__expf(-dd*dd*(1.f/3.78125f))); }
        featF[0] = v;
        float p4x = pj[12]-cax, p4y = pj[13]-cay, p4z = pj[14]-caz;
        v8s w = featF[1];
        w[0] = (short)f2bf(DOTR(0, p4x, p4y, p4z));
        w[1] = (short)f2bf(DOTR(1, p4x, p4y, p4z));
        w[2] = (short)f2bf(DOTR(2, p4x, p4y, p4z));
        featF[1] = w;
    } else if (hi == 2) {
        float inv = 1.f / (d + 1e-8f);
        float ux = dx*inv, uy = dy*inv, uz = dz*inv;
        float Rj[9];
        #pragma unroll
        for (int q = 0; q < 9; ++q) Rj[q] = R_ws[(size_t)j * 9 + q];
        #define ROT(b,c) (Ri[(b)*3]*Rj[(c)*3] + Ri[(b)*3+1]*Rj[(c)*3+1] + Ri[(b)*3+2]*Rj[(c)*3+2])
        v8s v;
        v[0] = (short)f2bf(DOTR(0, ux, uy, uz));
        v[1] = (short)f2bf(DOTR(1, ux, uy, uz));
        v[2] = (short)f2bf(DOTR(2, ux, uy, uz));
        v[3] = (short)f2bf(ROT(0,0));
        v[4] = (short)f2bf(ROT(0,1));
        v[5] = (short)f2bf(ROT(0,2));
        v[6] = (short)f2bf(ROT(1,0));
        v[7] = (short)f2bf(ROT(1,1));
        featF[0] = v;
        #undef ROT
    } else {
        float Rj[9];
        #pragma unroll
        for (int q = 0; q < 9; ++q) Rj[q] = R_ws[(size_t)j * 9 + q];
        #define ROT(b,c) (Ri[(b)*3]*Rj[(c)*3] + Ri[(b)*3+1]*Rj[(c)*3+1] + Ri[(b)*3+2]*Rj[(c)*3+2])
        float p0x = pj[0]-cax, p0y = pj[1]-cay, p0z = pj[2]-caz;
        v8s v;
        v[0] = (short)f2bf(ROT(1,2));
        v[1] = (short)f2bf(ROT(2,0));
        v[2] = (short)f2bf(ROT(2,1));
        v[3] = (short)f2bf(ROT(2,2));
        v[4] = (short)f2bf(DOTR(0, p0x, p0y, p0z));
        v[5] = (short)f2bf(DOTR(1, p0x, p0y, p0z));
        v[6] = (short)f2bf(DOTR(2, p0x, p0y, p0z));
        v[7] = (short)f2bf(DOTR(0, dx, dy, dz));
        featF[0] = v;
        #undef ROT
    }
    #undef DOTR

    // ---- P1: swapped pair GEMM; C[channel a*16+hi*4+r][row c15]; LN in-reg ----
    {
        v4f pacc[8];
        #pragma unroll
        for (int a = 0; a < 8; ++a) { pacc[a][0]=0.f; pacc[a][1]=0.f; pacc[a][2]=0.f; pacc[a][3]=0.f; }
        #pragma unroll
        for (int ks = 0; ks < 4; ++ks) {
            v8s bF = featF[ks];
            #pragma unroll
            for (int a = 0; a < 8; ++a) {
                v8s aF = *(const v8s*)&Wcomb[(size_t)(a*16 + c15) * 128 + ks*32 + hi*8];
                pacc[a] = __builtin_amdgcn_mfma_f32_16x16x32_bf16(aF, bF, pacc[a], 0, 0, 0);
            }
        }
        const float pm = (mi != 0 && mj != 0 && nb != -1) ? 1.f : 0.f;
        float s = 0.f, sq = 0.f;
        #pragma unroll
        for (int a = 0; a < 8; ++a) {
            float v0 = (pacc[a][0] + liR[a].x + ljR[a].x) * pm;
            float v1 = (pacc[a][1] + liR[a].y + ljR[a].y) * pm;
            float v2 = (pacc[a][2] + liR[a].z + ljR[a].z) * pm;
            float v3 = (pacc[a][3] + liR[a].w + ljR[a].w) * pm;
            pacc[a][0] = v0; pacc[a][1] = v1; pacc[a][2] = v2; pacc[a][3] = v3;
            s += v0 + v1 + v2 + v3;
            sq += v0*v0 + v1*v1 + v2*v2 + v3*v3;
        }
        s += __shfl_xor(s, 16, 64);  sq += __shfl_xor(sq, 16, 64);
        s += __shfl_xor(s, 32, 64);  sq += __shfl_xor(sq, 32, 64);
        const float mu = s * (1.f/128.f);
        const float rstd = rsqrtf(sq * (1.f/128.f) - mu*mu + 1e-5f);
        const float nm = -mu * rstd;
        #pragma unroll
        for (int a = 0; a < 8; ++a) {
            const int col0 = a*16 + hi*4;
            float4 sc = *(const float4*)&smalls[col0];
            float4 bb = *(const float4*)&smalls[128 + col0];
            v4s_t u;
            u[0] = (short)f2bf(fmaf(fmaf(pacc[a][0], rstd, nm), sc.x, bb.x));
            u[1] = (short)f2bf(fmaf(fmaf(pacc[a][1], rstd, nm), sc.y, bb.y));
            u[2] = (short)f2bf(fmaf(fmaf(pacc[a][2], rstd, nm), sc.z, bb.z));
            u[3] = (short)f2bf(fmaf(fmaf(pacc[a][3], rstd, nm), sc.w, bb.w));
            const int chunk = ((col0 >> 3) ^ sw) ;     // low-3-bit XOR, 16 chunks
            *(v4s_t*)&PB[brow * 128 + (chunk << 3) + (hi & 1) * 4] = u;
        }
    }
    __syncthreads();   // bar1: pairB ready

    // ---- P4: hidden = W1 x pairB; waves split 256 hcols; C[hcol][prow]; gelu -> HT ----
    {
        v4f acc[4][4];   // [a8 hcol-tile][bt row-group]
        #pragma unroll
        for (int a = 0; a < 4; ++a)
            #pragma unroll
            for (int b = 0; b < 4; ++b) { acc[a][b][0]=0.f; acc[a][b][1]=0.f; acc[a][b][2]=0.f; acc[a][b][3]=0.f; }
        #pragma unroll
        for (int ks = 0; ks < 4; ++ks) {
            v8s bFr[4];
            #pragma unroll
            for (int bt = 0; bt < 4; ++bt)
                bFr[bt] = *(const v8s*)&PB[(bt*16 + c15) * 128 + (((ks*4 + hi) ^ sw) << 3)];
            #pragma unroll
            for (int a8 = 0; a8 < 4; ++a8) {
                v8s aF = *(const v8s*)&W1T[(size_t)(wid*64 + a8*16 + c15) * 128 + ks*32 + hi*8];
                #pragma unroll
                for (int bt = 0; bt < 4; ++bt)
                    acc[a8][bt] = __builtin_amdgcn_mfma_f32_16x16x32_bf16(aF, bFr[bt], acc[a8][bt], 0, 0, 0);
            }
        }
        #pragma unroll
        for (int a8 = 0; a8 < 4; ++a8) {
            const int h0 = wid*64 + a8*16 + hi*4;
            float4 bv = *(const float4*)&smalls[256 + h0];
            const int chunk0 = h0 >> 3;               // 32 chunks (256-wide)
            #pragma unroll
            for (int bt = 0; bt < 4; ++bt) {
                const int r2 = bt*16 + c15;
                v4s_t u;
                u[0] = (short)f2bf(fast_gelu(acc[a8][bt][0] + bv.x));
                u[1] = (short)f2bf(fast_gelu(acc[a8][bt][1] + bv.y));
                u[2] = (short)f2bf(fast_gelu(acc[a8][bt][2] + bv.z));
                u[3] = (short)f2bf(fast_gelu(acc[a8][bt][3] + bv.w));
                *(v4s_t*)&HT[r2 * 256 + ((chunk0 ^ (r2 & 7)) << 3) + (hi & 1) * 4] = u;
            }
        }
    }
    __syncthreads();   // bar2: HT ready

    // ---- P5: swapped MLP2; C[bin][row c15]; softmax in-reg; direct store ----
    {
        v4f acc2[4];
        #pragma unroll
        for (int a = 0; a < 4; ++a) { acc2[a][0]=0.f; acc2[a][1]=0.f; acc2[a][2]=0.f; acc2[a][3]=0.f; }
        #pragma unroll
        for (int ks = 0; ks < 8; ++ks) {
            v8s bF = *(const v8s*)&HT[brow * 256 + (((ks*4 + hi) ^ sw) << 3)];
            #pragma unroll
            for (int a = 0; a < 4; ++a) {
                v8s aF = *(const v8s*)&W2T[(size_t)(a*16 + c15) * 256 + ks*32 + hi*8];
                acc2[a] = __builtin_amdgcn_mfma_f32_16x16x32_bf16(aF, bF, acc2[a], 0, 0, 0);
            }
        }
        float lv[16];
        #pragma unroll
        for (int a = 0; a < 4; ++a) {
            float4 bv = *(const float4*)&smalls[512 + a*16 + hi*4];
            lv[a*4+0] = acc2[a][0] + bv.x;
            lv[a*4+1] = acc2[a][1] + bv.y;
            lv[a*4+2] = acc2[a][2] + bv.z;
            lv[a*4+3] = acc2[a][3] + bv.w;
        }
        float M = lv[0];
        #pragma unroll
        for (int q = 1; q < 16; ++q) M = fmaxf(M, lv[q]);
        M = fmaxf(M, __shfl_xor(M, 16, 64));
        M = fmaxf(M, __shfl_xor(M, 32, 64));
        float S = 0.f;
        #pragma unroll
        for (int q = 0; q < 16; ++q) S += __expf(lv[q] - M);
        S += __shfl_xor(S, 16, 64);
        S += __shfl_xor(S, 32, 64);
        const float lz = M + __logf(S);
        #pragma unroll
        for (int a = 0; a < 4; ++a) {
            float4 o;
            o.x = lv[a*4+0] - lz; o.y = lv[a*4+1] - lz;
            o.z = lv[a*4+2] - lz; o.w = lv[a*4+3] - lz;
            *(float4*)&out[(size_t)row * 64 + a*16 + hi*4] = o;
        }
    }
}

extern "C" void kernel_launch(void* const* d_in, const int* in_sizes, int n_in,
                              void* d_out, int out_size, void* d_ws, size_t ws_size,
                              hipStream_t stream) {
    (void)in_sizes; (void)n_in; (void)out_size; (void)ws_size;
    const float* local   = (const float*)d_in[0];
    const float* pos     = (const float*)d_in[1];
    const int* neighbours= (const int*)d_in[2];
    const int* resi      = (const int*)d_in[3];
    const int* chain     = (const int*)d_in[4];
    const int* batch     = (const int*)d_in[5];
    const int* mask      = (const int*)d_in[6];
    const float* W_relpos= (const float*)d_in[7];
    const float* W_dist  = (const float*)d_in[8];
    const float* W_dir   = (const float*)d_in[9];
    const float* W_rot   = (const float*)d_in[10];
    const float* W_pvec  = (const float*)d_in[11];
    const float* W_loc_i = (const float*)d_in[12];
    const float* W_loc_j = (const float*)d_in[13];
    const float* ln_scale= (const float*)d_in[14];
    const float* ln_bias = (const float*)d_in[15];
    const float* W1      = (const float*)d_in[16];
    const float* b1      = (const float*)d_in[17];
    const float* W2      = (const float*)d_in[18];
    const float* b2      = (const float*)d_in[19];
    float* out = (float*)d_out;

    float* R_ws    = (float*)d_ws;                          // 8192*9 f32
    float* loci_ws = R_ws + (size_t)N_NODES * 9;            // 8192*128 f32
    float* locj_ws = loci_ws + (size_t)N_NODES * PDIM;      // 8192*128 f32
    ushort_t* Wcomb = (ushort_t*)(locj_ws + (size_t)N_NODES * PDIM); // 128*128
    ushort_t* W1T   = Wcomb + 16384;                        // 256*128
    ushort_t* W2T   = W1T + 32768;                          // 64*256
    ushort_t* W_locT= W2T + 16384;                          // 256*256

    hipLaunchKernelGGL(prep_kernel, dim3(512), dim3(256), 0, stream,
                       W_dist, W_dir, W_rot, W_pvec, W_relpos, W1, W2,
                       W_loc_i, W_loc_j, Wcomb, W1T, W2T, W_locT);
    hipLaunchKernelGGL(locframe_kernel, dim3(N_NODES / 32), dim3(256), 0, stream,
                       local, pos, W_locT, R_ws, loci_ws, locj_ws);
    hipLaunchKernelGGL(pair_kernel, dim3(N_NODES / 2), dim3(256), 0, stream,
                       pos, neighbours, resi, chain, batch, mask,
                       ln_scale, ln_bias, b1, b2,
                       R_ws, loci_ws, locj_ws, Wcomb, W1T, W2T, out);
}

// Round 7
// 141.054 us; speedup vs baseline: 2.2154x; 1.5369x over previous
//
#include <hip/hip_runtime.h>
#include <hip/hip_bf16.h>
#include <math.h>

#define N_NODES 8192
#define KNBR    32
#define PDIM    128
#define BINS    64
#define REL_CLIP 32
#define REL_DIM  66

typedef unsigned short ushort_t;
typedef short v8s  __attribute__((ext_vector_type(8)));
typedef short v4s_t __attribute__((ext_vector_type(4)));
typedef float v4f  __attribute__((ext_vector_type(4)));

__device__ __forceinline__ ushort_t f2bf(float f) {
    union { __hip_bfloat16 b; ushort_t u; } cv;
    cv.b = __float2bfloat16(f);
    return cv.u;
}
__device__ __forceinline__ unsigned int pk2bf(float lo, float hiv) {
    union { __hip_bfloat162 h2; unsigned int u; } cv;
    cv.h2 = __float22bfloat162_rn(make_float2(lo, hiv));
    return cv.u;
}
// gelu_tanh(x) == x * sigmoid(2*0.7978845608*(x + 0.044715 x^3)) (exact identity)
__device__ __forceinline__ float fast_gelu(float x) {
    float x2 = x * x;
    float y = x * fmaf(x2, 0.07135481627f, 1.5957691216f);
    float e = __expf(-y);
    return x / (1.f + e);
}

// ---------------- prep: bf16 transposed/combined weights ----------------
__global__ __launch_bounds__(256) void prep_kernel(
    const float* __restrict__ W_dist, const float* __restrict__ W_dir,
    const float* __restrict__ W_rot, const float* __restrict__ W_pvec,
    const float* __restrict__ W_relpos,
    const float* __restrict__ W1, const float* __restrict__ W2,
    const float* __restrict__ W_loc_i, const float* __restrict__ W_loc_j,
    ushort_t* __restrict__ Wcomb, ushort_t* __restrict__ W1T,
    ushort_t* __restrict__ W2T, ushort_t* __restrict__ W_locT)
{
    int idx = blockIdx.x * 256 + threadIdx.x;
    if (idx < 16384) {
        int col = idx >> 7, k = idx & 127;
        float v = 0.f;
        if (k < 16)       v = W_dist[k * PDIM + col];
        else if (k < 19)  v = W_dir[(k - 16) * PDIM + col];
        else if (k < 28)  v = W_rot[(k - 19) * PDIM + col];
        else if (k < 43)  v = W_pvec[(k - 28) * PDIM + col];
        else if (k < 109) v = W_relpos[(size_t)(k - 43) * PDIM + col];
        Wcomb[idx] = f2bf(v);
    } else if (idx < 49152) {
        int o = idx - 16384;
        int col = o >> 7, k = o & 127;
        W1T[o] = f2bf(W1[(size_t)k * 256 + col]);
    } else if (idx < 65536) {
        int o = idx - 49152;
        int col = o >> 8, k = o & 255;
        W2T[o] = f2bf(W2[(size_t)k * BINS + col]);
    } else if (idx < 131072) {
        int o = idx - 65536;
        int oc = o >> 8, k = o & 255;
        float v = (oc < 128) ? W_loc_i[(size_t)k * 128 + oc]
                             : W_loc_j[(size_t)k * 128 + (oc - 128)];
        W_locT[o] = f2bf(v);
    }
}

// ---------------- locframe: frames + MFMA local projections ----------------
__global__ __launch_bounds__(256) void locframe_kernel(
    const float* __restrict__ local, const float* __restrict__ pos,
    const ushort_t* __restrict__ W_locT,
    float* __restrict__ R_ws, float* __restrict__ loci_ws, float* __restrict__ locj_ws)
{
    __shared__ __align__(16) ushort_t LB[32 * 264];
    const int tid = threadIdx.x;
    const int base = blockIdx.x * 32;
    const int wid = tid >> 6, lane = tid & 63, c15 = lane & 15, hi = lane >> 4;

    if (tid < 32) {  // frames
        const int n = base + tid;
        const float* pp = pos + (size_t)n * 15;
        float nx = pp[0], ny = pp[1], nz = pp[2];
        float cax = pp[3], cay = pp[4], caz = pp[5];
        float cx = pp[6], cy = pp[7], cz = pp[8];
        float e1x = cx - cax, e1y = cy - cay, e1z = cz - caz;
        float n1 = sqrtf(e1x*e1x + e1y*e1y + e1z*e1z) + 1e-8f;
        e1x /= n1; e1y /= n1; e1z /= n1;
        float v2x = nx - cax, v2y = ny - cay, v2z = nz - caz;
        float dp = v2x*e1x + v2y*e1y + v2z*e1z;
        float wx = v2x - dp*e1x, wy = v2y - dp*e1y, wz = v2z - dp*e1z;
        float n2 = sqrtf(wx*wx + wy*wy + wz*wz) + 1e-8f;
        float e2x = wx/n2, e2y = wy/n2, e2z = wz/n2;
        float* R = R_ws + (size_t)n * 9;
        R[0] = e1x; R[1] = e1y; R[2] = e1z;
        R[3] = e2x; R[4] = e2y; R[5] = e2z;
        R[6] = e1y*e2z - e1z*e2y;
        R[7] = e1z*e2x - e1x*e2z;
        R[8] = e1x*e2y - e1y*e2x;
    }
    #pragma unroll
    for (int it = 0; it < 8; ++it) {
        int f = tid + it * 256;
        int row = f >> 6, kc = f & 63;
        float4 L = *(const float4*)&local[((size_t)(base + row)) * 256 + kc * 4];
        unsigned int u01 = pk2bf(L.x, L.y), u23 = pk2bf(L.z, L.w);
        uint2 w8; w8.x = u01; w8.y = u23;
        *(uint2*)&LB[row * 264 + kc * 4] = w8;
    }
    __syncthreads();

    v4f acc[4][2];
    #pragma unroll
    for (int a = 0; a < 4; ++a)
        #pragma unroll
        for (int b = 0; b < 2; ++b) { acc[a][b][0]=0.f; acc[a][b][1]=0.f; acc[a][b][2]=0.f; acc[a][b][3]=0.f; }
    #pragma unroll
    for (int ks = 0; ks < 8; ++ks) {
        v8s bF[2];
        #pragma unroll
        for (int bt = 0; bt < 2; ++bt)
            bF[bt] = *(const v8s*)&LB[(bt*16 + c15) * 264 + ks*32 + hi*8];
        #pragma unroll
        for (int act = 0; act < 4; ++act) {
            v8s aF = *(const v8s*)&W_locT[(size_t)(wid*64 + act*16 + c15) * 256 + ks*32 + hi*8];
            #pragma unroll
            for (int bt = 0; bt < 2; ++bt)
                acc[act][bt] = __builtin_amdgcn_mfma_f32_16x16x32_bf16(aF, bF[bt], acc[act][bt], 0, 0, 0);
        }
    }
    #pragma unroll
    for (int act = 0; act < 4; ++act) {
        const int oc0 = wid*64 + act*16 + hi*4;
        #pragma unroll
        for (int bt = 0; bt < 2; ++bt) {
            const int lrow = bt*16 + c15;
            float4 v;
            v.x = acc[act][bt][0]; v.y = acc[act][bt][1];
            v.z = acc[act][bt][2]; v.w = acc[act][bt][3];
            if (oc0 < 128)
                *(float4*)&loci_ws[(size_t)(base + lrow) * 128 + oc0] = v;
            else
                *(float4*)&locj_ws[(size_t)(base + lrow) * 128 + (oc0 - 128)] = v;
        }
    }
}

// ---------------- pair kernel: 4096 blocks x 256 thr, 64 rows (2 nodes) ----------------
// wave-split weights; in-reg LN + softmax via redS; HT ping-pong halves
__global__ __launch_bounds__(256, 4) void pair_kernel(
    const float* __restrict__ pos, const int* __restrict__ neighbours,
    const int* __restrict__ resi, const int* __restrict__ chain,
    const int* __restrict__ batch, const int* __restrict__ mask,
    const float* __restrict__ ln_scale, const float* __restrict__ ln_bias,
    const float* __restrict__ b1, const float* __restrict__ b2,
    const float* __restrict__ R_ws, const float* __restrict__ loci_ws,
    const float* __restrict__ locj_ws,
    const ushort_t* __restrict__ Wcomb, const ushort_t* __restrict__ W1T,
    const ushort_t* __restrict__ W2T, float* __restrict__ out)
{
    __shared__ __align__(16) ushort_t SH0[64 * 128];   // featB -> pairB (16KB, aliased)
    __shared__ __align__(16) ushort_t HT[64 * 128];    // hidden half (16KB, ping-pong)
    __shared__ float2 redS[64][5];                     // cross-wave reduce (pad col)
    __shared__ float smalls[576];                      // lnsc|lnb|b1|b2

    const int tid = threadIdx.x;
    const int ib = blockIdx.x;
    const int base = ib * 2;
    const int wid = tid >> 6, lane = tid & 63, c15 = lane & 15, hi = lane >> 4;
    const int brow = wid * 16 + c15;     // own row for feature gen
    const int sw = c15 & 7;

    if (tid < 144) {
        int t4 = tid * 4;
        float4 v;
        if (tid < 32)       v = *(const float4*)&ln_scale[t4];
        else if (tid < 64)  v = *(const float4*)&ln_bias[t4 - 128];
        else if (tid < 128) v = *(const float4*)&b1[t4 - 256];
        else                v = *(const float4*)&b2[t4 - 512];
        *(float4*)&smalls[t4] = v;
    }

    // ---- neighbor indices for the 4 rows this lane touches in epilogues ----
    int nbv[4], jv[4];
    #pragma unroll
    for (int bt = 0; bt < 4; ++bt) {
        const int rr = bt * 16 + c15;
        nbv[bt] = neighbours[(size_t)(base + (bt >> 1)) * KNBR + (rr & 31)];
        jv[bt] = nbv[bt] < 0 ? 0 : nbv[bt];
    }
    const int node_own = base + (wid >> 1);
    const int j_own = wid == 0 ? jv[0] : wid == 1 ? jv[1] : wid == 2 ? jv[2] : jv[3];

    // ---- own-row features -> SH0 (featB) ----
    {
        int rel = resi[j_own] - resi[node_own];
        rel = rel < -REL_CLIP ? -REL_CLIP : (rel > REL_CLIP ? REL_CLIP : rel);
        rel += REL_CLIP;
        const int code = ((chain[j_own] == chain[node_own]) && (batch[j_own] == batch[node_own]))
                         ? rel : (REL_DIM - 1);
        float Ri[9];
        #pragma unroll
        for (int q = 0; q < 9; ++q) Ri[q] = R_ws[(size_t)node_own * 9 + q];
        const float cax = pos[(size_t)node_own*15 + 3], cay = pos[(size_t)node_own*15 + 4], caz = pos[(size_t)node_own*15 + 5];
        const float* pj = pos + (size_t)j_own * 15;
        const float dx = pj[3] - cax, dy = pj[4] - cay, dz = pj[5] - caz;

        v8s featF[4];
        #pragma unroll
        for (int ks = 1; ks < 4; ++ks) {
            const int cb = ks*32 + hi*8 - 43;
            v8s v;
            #pragma unroll
            for (int t = 0; t < 8; ++t) v[t] = (short)((code == cb + t) ? 0x3F80 : 0);
            featF[ks] = v;
        }
        #define DOTR(b,X,Y,Z) (Ri[(b)*3]*(X) + Ri[(b)*3+1]*(Y) + Ri[(b)*3+2]*(Z))
        const float d = sqrtf(dx*dx + dy*dy + dz*dz);
        if (hi == 0) {
            v8s v;
            #pragma unroll
            for (int r = 0; r < 8; ++r) { float dd = d - (22.f/15.f)*r; v[r] = (short)f2bf(__expf(-dd*dd*(1.f/3.78125f))); }
            featF[0] = v;
            float p2x = pj[6]-cax, p2y = pj[7]-cay, p2z = pj[8]-caz;
            float p3x = pj[9]-cax, p3y = pj[10]-cay, p3z = pj[11]-caz;
            v8s w;
            w[0] = (short)f2bf(DOTR(1, dx, dy, dz));
            w[1] = (short)f2bf(DOTR(2, dx, dy, dz));
            w[2] = (short)f2bf(DOTR(0, p2x, p2y, p2z));
            w[3] = (short)f2bf(DOTR(1, p2x, p2y, p2z));
            w[4] = (short)f2bf(DOTR(2, p2x, p2y, p2z));
            w[5] = (short)f2bf(DOTR(0, p3x, p3y, p3z));
            w[6] = (short)f2bf(DOTR(1, p3x, p3y, p3z));
            w[7] = (short)f2bf(DOTR(2, p3x, p3y, p3z));
            featF[1] = w;
        } else if (hi == 1) {
            v8s v;
            #pragma unroll
            for (int r = 0; r < 8; ++r) { float dd = d - (22.f/15.f)*(r+8); v[r] = (short)f2bf(__expf(-dd*dd*(1.f/3.78125f))); }
            featF[0] = v;
            float p4x = pj[12]-cax, p4y = pj[13]-cay, p4z = pj[14]-caz;
            v8s w = featF[1];
            w[0] = (short)f2bf(DOTR(0, p4x, p4y, p4z));
            w[1] = (short)f2bf(DOTR(1, p4x, p4y, p4z));
            w[2] = (short)f2bf(DOTR(2, p4x, p4y, p4z));
            featF[1] = w;
        } else if (hi == 2) {
            float inv = 1.f / (d + 1e-8f);
            float ux = dx*inv, uy = dy*inv, uz = dz*inv;
            float Rj[9];
            #pragma unroll
            for (int q = 0; q < 9; ++q) Rj[q] = R_ws[(size_t)j_own * 9 + q];
            #define ROT(b,c) (Ri[(b)*3]*Rj[(c)*3] + Ri[(b)*3+1]*Rj[(c)*3+1] + Ri[(b)*3+2]*Rj[(c)*3+2])
            v8s v;
            v[0] = (short)f2bf(DOTR(0, ux, uy, uz));
            v[1] = (short)f2bf(DOTR(1, ux, uy, uz));
            v[2] = (short)f2bf(DOTR(2, ux, uy, uz));
            v[3] = (short)f2bf(ROT(0,0));
            v[4] = (short)f2bf(ROT(0,1));
            v[5] = (short)f2bf(ROT(0,2));
            v[6] = (short)f2bf(ROT(1,0));
            v[7] = (short)f2bf(ROT(1,1));
            featF[0] = v;
            #undef ROT
        } else {
            float Rj[9];
            #pragma unroll
            for (int q = 0; q < 9; ++q) Rj[q] = R_ws[(size_t)j_own * 9 + q];
            #define ROT(b,c) (Ri[(b)*3]*Rj[(c)*3] + Ri[(b)*3+1]*Rj[(c)*3+1] + Ri[(b)*3+2]*Rj[(c)*3+2])
            float p0x = pj[0]-cax, p0y = pj[1]-cay, p0z = pj[2]-caz;
            v8s v;
            v[0] = (short)f2bf(ROT(1,2));
            v[1] = (short)f2bf(ROT(2,0));
            v[2] = (short)f2bf(ROT(2,1));
            v[3] = (short)f2bf(ROT(2,2));
            v[4] = (short)f2bf(DOTR(0, p0x, p0y, p0z));
            v[5] = (short)f2bf(DOTR(1, p0x, p0y, p0z));
            v[6] = (short)f2bf(DOTR(2, p0x, p0y, p0z));
            v[7] = (short)f2bf(DOTR(0, dx, dy, dz));
            featF[0] = v;
            #undef ROT
        }
        #undef DOTR
        #pragma unroll
        for (int ks = 0; ks < 4; ++ks)
            *(v8s*)&SH0[brow * 128 + (((ks*4 + hi) ^ sw) << 3)] = featF[ks];
    }
    __syncthreads();   // bar1: featB + smalls ready

    // ---- P1: pair GEMM, wave-split channels (wid*32..+32), rows shared ----
    float mu0, mu1, mu2, mu3, rs0, rs1, rs2, rs3;
    {
        v4f pacc[2][4];
        #pragma unroll
        for (int at = 0; at < 2; ++at)
            #pragma unroll
            for (int bt = 0; bt < 4; ++bt) { pacc[at][bt][0]=0.f; pacc[at][bt][1]=0.f; pacc[at][bt][2]=0.f; pacc[at][bt][3]=0.f; }
        #pragma unroll
        for (int ks = 0; ks < 4; ++ks) {
            v8s bF[4];
            #pragma unroll
            for (int bt = 0; bt < 4; ++bt)
                bF[bt] = *(const v8s*)&SH0[(bt*16 + c15) * 128 + (((ks*4 + hi) ^ sw) << 3)];
            #pragma unroll
            for (int at = 0; at < 2; ++at) {
                v8s aF = *(const v8s*)&Wcomb[(size_t)((wid*2 + at)*16 + c15) * 128 + ks*32 + hi*8];
                #pragma unroll
                for (int bt = 0; bt < 4; ++bt)
                    pacc[at][bt] = __builtin_amdgcn_mfma_f32_16x16x32_bf16(aF, bF[bt], pacc[at][bt], 0, 0, 0);
            }
        }
        // epilogue: loc adds + mask + LN partials
        const int mi0 = mask[base], mi1 = mask[base + 1];
        float pmv[4];
        #pragma unroll
        for (int bt = 0; bt < 4; ++bt) {
            const int min_ = (bt < 2) ? mi0 : mi1;
            pmv[bt] = (min_ != 0 && mask[jv[bt]] != 0 && nbv[bt] != -1) ? 1.f : 0.f;
        }
        float4 liA[2][2], ljA[2][4];
        #pragma unroll
        for (int at = 0; at < 2; ++at) {
            const int ch0 = wid*32 + at*16 + hi*4;
            liA[at][0] = *(const float4*)&loci_ws[(size_t)base * 128 + ch0];
            liA[at][1] = *(const float4*)&loci_ws[(size_t)(base + 1) * 128 + ch0];
            #pragma unroll
            for (int bt = 0; bt < 4; ++bt)
                ljA[at][bt] = *(const float4*)&locj_ws[(size_t)jv[bt] * 128 + ch0];
        }
        float sA[4], qA[4];
        #pragma unroll
        for (int bt = 0; bt < 4; ++bt) {
            float s = 0.f, q = 0.f;
            #pragma unroll
            for (int at = 0; at < 2; ++at) {
                const float4 li = (bt < 2) ? liA[at][0] : liA[at][1];
                const float4 lj = ljA[at][bt];
                float v0 = (pacc[at][bt][0] + li.x + lj.x) * pmv[bt];
                float v1 = (pacc[at][bt][1] + li.y + lj.y) * pmv[bt];
                float v2 = (pacc[at][bt][2] + li.z + lj.z) * pmv[bt];
                float v3 = (pacc[at][bt][3] + li.w + lj.w) * pmv[bt];
                pacc[at][bt][0] = v0; pacc[at][bt][1] = v1; pacc[at][bt][2] = v2; pacc[at][bt][3] = v3;
                s += v0 + v1 + v2 + v3;
                q += v0*v0 + v1*v1 + v2*v2 + v3*v3;
            }
            s += __shfl_xor(s, 16, 64);  q += __shfl_xor(q, 16, 64);
            s += __shfl_xor(s, 32, 64);  q += __shfl_xor(q, 32, 64);
            sA[bt] = s; qA[bt] = q;
        }
        // lane with hi==bt publishes row (hi*16+c15) partial for this wave
        {
            float ssel = hi == 0 ? sA[0] : hi == 1 ? sA[1] : hi == 2 ? sA[2] : sA[3];
            float qsel = hi == 0 ? qA[0] : hi == 1 ? qA[1] : hi == 2 ? qA[2] : qA[3];
            redS[lane][wid] = make_float2(ssel, qsel);
        }
        __syncthreads();   // bar2: redS ready; featB reads done
        #pragma unroll
        for (int bt = 0; bt < 4; ++bt) {
            const int rr = bt*16 + c15;
            float2 r0 = redS[rr][0], r1 = redS[rr][1], r2 = redS[rr][2], r3 = redS[rr][3];
            float s = r0.x + r1.x + r2.x + r3.x;
            float q = r0.y + r1.y + r2.y + r3.y;
            float mu = s * (1.f/128.f);
            float rs = rsqrtf(q * (1.f/128.f) - mu*mu + 1e-5f);
            if (bt == 0) { mu0 = mu; rs0 = rs; }
            else if (bt == 1) { mu1 = mu; rs1 = rs; }
            else if (bt == 2) { mu2 = mu; rs2 = rs; }
            else { mu3 = mu; rs3 = rs; }
        }
        // normalize -> pairB (over featB space; all reads completed before bar2)
        #pragma unroll
        for (int at = 0; at < 2; ++at) {
            const int ch0 = wid*32 + at*16 + hi*4;
            const float4 sc = *(const float4*)&smalls[ch0];
            const float4 bb = *(const float4*)&smalls[128 + ch0];
            const int chA = (wid*4 + at*2 + (hi >> 1));
            #pragma unroll
            for (int bt = 0; bt < 4; ++bt) {
                const float mu = bt == 0 ? mu0 : bt == 1 ? mu1 : bt == 2 ? mu2 : mu3;
                const float rs = bt == 0 ? rs0 : bt == 1 ? rs1 : bt == 2 ? rs2 : rs3;
                const float nm = -mu * rs;
                float v0 = fmaf(fmaf(pacc[at][bt][0], rs, nm), sc.x, bb.x);
                float v1 = fmaf(fmaf(pacc[at][bt][1], rs, nm), sc.y, bb.y);
                float v2 = fmaf(fmaf(pacc[at][bt][2], rs, nm), sc.z, bb.z);
                float v3 = fmaf(fmaf(pacc[at][bt][3], rs, nm), sc.w, bb.w);
                uint2 w8; w8.x = pk2bf(v0, v1); w8.y = pk2bf(v2, v3);
                const int row = bt*16 + c15;
                *(uint2*)&SH0[row * 128 + ((chA ^ sw) << 3) + (hi & 1) * 4] = w8;
            }
        }
    }
    __syncthreads();   // bar3: pairB ready

    // ---- P4 halves + P5 partial accumulate ----
    v4f acc5[4];
    #pragma unroll
    for (int bt = 0; bt < 4; ++bt) { acc5[bt][0]=0.f; acc5[bt][1]=0.f; acc5[bt][2]=0.f; acc5[bt][3]=0.f; }
    #pragma unroll
    for (int half = 0; half < 2; ++half) {
        v4f acc4[2][4];
        #pragma unroll
        for (int at = 0; at < 2; ++at)
            #pragma unroll
            for (int bt = 0; bt < 4; ++bt) { acc4[at][bt][0]=0.f; acc4[at][bt][1]=0.f; acc4[at][bt][2]=0.f; acc4[at][bt][3]=0.f; }
        #pragma unroll
        for (int ks = 0; ks < 4; ++ks) {
            v8s bF[4];
            #pragma unroll
            for (int bt = 0; bt < 4; ++bt)
                bF[bt] = *(const v8s*)&SH0[(bt*16 + c15) * 128 + (((ks*4 + hi) ^ sw) << 3)];
            #pragma unroll
            for (int at = 0; at < 2; ++at) {
                v8s aF = *(const v8s*)&W1T[(size_t)(half*128 + wid*32 + at*16 + c15) * 128 + ks*32 + hi*8];
                #pragma unroll
                for (int bt = 0; bt < 4; ++bt)
                    acc4[at][bt] = __builtin_amdgcn_mfma_f32_16x16x32_bf16(aF, bF[bt], acc4[at][bt], 0, 0, 0);
            }
        }
        // gelu + write HT (half buffer)
        #pragma unroll
        for (int at = 0; at < 2; ++at) {
            const int h0 = half*128 + wid*32 + at*16 + hi*4;
            const float4 bv = *(const float4*)&smalls[256 + h0];
            const int chA = (wid*4 + at*2 + (hi >> 1));
            #pragma unroll
            for (int bt = 0; bt < 4; ++bt) {
                float g0 = fast_gelu(acc4[at][bt][0] + bv.x);
                float g1 = fast_gelu(acc4[at][bt][1] + bv.y);
                float g2 = fast_gelu(acc4[at][bt][2] + bv.z);
                float g3 = fast_gelu(acc4[at][bt][3] + bv.w);
                uint2 w8; w8.x = pk2bf(g0, g1); w8.y = pk2bf(g2, g3);
                const int row = bt*16 + c15;
                *(uint2*)&HT[row * 128 + ((chA ^ sw) << 3) + (hi & 1) * 4] = w8;
            }
        }
        __syncthreads();   // HT half ready
        // P5 partial over this half's 128 k
        #pragma unroll
        for (int ks = 0; ks < 4; ++ks) {
            v8s aF = *(const v8s*)&W2T[(size_t)(wid*16 + c15) * 256 + half*128 + ks*32 + hi*8];
            #pragma unroll
            for (int bt = 0; bt < 4; ++bt) {
                v8s bF = *(const v8s*)&HT[(bt*16 + c15) * 128 + (((ks*4 + hi) ^ sw) << 3)];
                acc5[bt] = __builtin_amdgcn_mfma_f32_16x16x32_bf16(aF, bF, acc5[bt], 0, 0, 0);
            }
        }
        if (half == 0) __syncthreads();   // HT reads done before overwrite
    }

    // ---- softmax: bins split (wid,hi,r); per-wave (m,s) -> redS -> combine ----
    {
        const float4 bv = *(const float4*)&smalls[512 + wid*16 + hi*4];
        float mW[4], sW[4];
        #pragma unroll
        for (int bt = 0; bt < 4; ++bt) {
            acc5[bt][0] += bv.x; acc5[bt][1] += bv.y; acc5[bt][2] += bv.z; acc5[bt][3] += bv.w;
            float m = fmaxf(fmaxf(acc5[bt][0], acc5[bt][1]), fmaxf(acc5[bt][2], acc5[bt][3]));
            m = fmaxf(m, __shfl_xor(m, 16, 64));
            m = fmaxf(m, __shfl_xor(m, 32, 64));
            float s = __expf(acc5[bt][0] - m) + __expf(acc5[bt][1] - m)
                    + __expf(acc5[bt][2] - m) + __expf(acc5[bt][3] - m);
            s += __shfl_xor(s, 16, 64);
            s += __shfl_xor(s, 32, 64);
            mW[bt] = m; sW[bt] = s;
        }
        {
            float msel = hi == 0 ? mW[0] : hi == 1 ? mW[1] : hi == 2 ? mW[2] : mW[3];
            float ssel = hi == 0 ? sW[0] : hi == 1 ? sW[1] : hi == 2 ? sW[2] : sW[3];
            redS[lane][wid] = make_float2(msel, ssel);
        }
        __syncthreads();   // redS(softmax) ready
        #pragma unroll
        for (int bt = 0; bt < 4; ++bt) {
            const int rr = bt*16 + c15;
            float2 r0 = redS[rr][0], r1 = redS[rr][1], r2 = redS[rr][2], r3 = redS[rr][3];
            float M = fmaxf(fmaxf(r0.x, r1.x), fmaxf(r2.x, r3.x));
            float S = r0.y * __expf(r0.x - M) + r1.y * __expf(r1.x - M)
                    + r2.y * __expf(r2.x - M) + r3.y * __expf(r3.x - M);
            const float lz = M + __logf(S);
            float4 o;
            o.x = acc5[bt][0] - lz; o.y = acc5[bt][1] - lz;
            o.z = acc5[bt][2] - lz; o.w = acc5[bt][3] - lz;
            *(float4*)&out[((size_t)(ib * 64 + rr)) * 64 + wid*16 + hi*4] = o;
        }
    }
}

extern "C" void kernel_launch(void* const* d_in, const int* in_sizes, int n_in,
                              void* d_out, int out_size, void* d_ws, size_t ws_size,
                              hipStream_t stream) {
    (void)in_sizes; (void)n_in; (void)out_size; (void)ws_size;
    const float* local   = (const float*)d_in[0];
    const float* pos     = (const float*)d_in[1];
    const int* neighbours= (const int*)d_in[2];
    const int* resi      = (const int*)d_in[3];
    const int* chain     = (const int*)d_in[4];
    const int* batch     = (const int*)d_in[5];
    const int* mask      = (const int*)d_in[6];
    const float* W_relpos= (const float*)d_in[7];
    const float* W_dist  = (const float*)d_in[8];
    const float* W_dir   = (const float*)d_in[9];
    const float* W_rot   = (const float*)d_in[10];
    const float* W_pvec  = (const float*)d_in[11];
    const float* W_loc_i = (const float*)d_in[12];
    const float* W_loc_j = (const float*)d_in[13];
    const float* ln_scale= (const float*)d_in[14];
    const float* ln_bias = (const float*)d_in[15];
    const float* W1      = (const float*)d_in[16];
    const float* b1      = (const float*)d_in[17];
    const float* W2      = (const float*)d_in[18];
    const float* b2      = (const float*)d_in[19];
    float* out = (float*)d_out;

    float* R_ws    = (float*)d_ws;                          // 8192*9 f32
    float* loci_ws = R_ws + (size_t)N_NODES * 9;            // 8192*128 f32
    float* locj_ws = loci_ws + (size_t)N_NODES * PDIM;      // 8192*128 f32
    ushort_t* Wcomb = (ushort_t*)(locj_ws + (size_t)N_NODES * PDIM); // 128*128
    ushort_t* W1T   = Wcomb + 16384;                        // 256*128
    ushort_t* W2T   = W1T + 32768;                          // 64*256
    ushort_t* W_locT= W2T + 16384;                          // 256*256

    hipLaunchKernelGGL(prep_kernel, dim3(512), dim3(256), 0, stream,
                       W_dist, W_dir, W_rot, W_pvec, W_relpos, W1, W2,
                       W_loc_i, W_loc_j, Wcomb, W1T, W2T, W_locT);
    hipLaunchKernelGGL(locframe_kernel, dim3(N_NODES / 32), dim3(256), 0, stream,
                       local, pos, W_locT, R_ws, loci_ws, locj_ws);
    hipLaunchKernelGGL(pair_kernel, dim3(N_NODES / 2), dim3(256), 0, stream,
                       pos, neighbours, resi, chain, batch, mask,
                       ln_scale, ln_bias, b1, b2,
                       R_ws, loci_ws, locj_ws, Wcomb, W1T, W2T, out);
}